// Round 1
// baseline (232.750 us; speedup 1.0000x reference)
//
#include <hip/hip_runtime.h>

#define NPTS 262144
#define P1 2654435761u
#define P2 805459861u
#define TMASK 0x7FFFFu

__device__ __forceinline__ float sigmoidf_fast(float v) {
    return 1.0f / (1.0f + __expf(-v));
}

extern "C" __global__ void __launch_bounds__(256) ngp_fused(
    const float* __restrict__ xin, const float* __restrict__ din,
    const float* __restrict__ tbl,
    const float* __restrict__ dW1, const float* __restrict__ db1,
    const float* __restrict__ dW2, const float* __restrict__ db2,
    const float* __restrict__ cW1, const float* __restrict__ cb1,
    const float* __restrict__ cW2, const float* __restrict__ cb2,
    const float* __restrict__ cW3, const float* __restrict__ cb3,
    float* __restrict__ out)
{
    const int gid = blockIdx.x * 256 + (int)threadIdx.x;

    const float x0 = xin[3 * gid + 0];
    const float x1 = xin[3 * gid + 1];
    const float x2 = xin[3 * gid + 2];
    const float d0 = din[3 * gid + 0];
    const float d1 = din[3 * gid + 1];
    const float d2 = din[3 * gid + 2];

    const float xn0 = x0 / 3.0f, xn1 = x1 / 3.0f, xn2 = x2 / 3.0f;
    const bool mask = (fabsf(xn0) < 0.5f) & (fabsf(xn1) < 0.5f) & (fabsf(xn2) < 0.5f);
    const float p0 = xn0 + 0.5f, p1 = xn1 + 0.5f, p2 = xn2 + 0.5f;

    // ---- hash-grid encode: 16 levels x 8 corners, trilinear ----
    const float NLs[16] = {16.f, 22.f, 30.f, 42.f, 58.f, 80.f, 111.f, 153.f,
                           212.f, 294.f, 406.f, 561.f, 776.f, 1072.f, 1482.f, 2048.f};
    float feats[32];
    #pragma unroll
    for (int l = 0; l < 16; ++l) {
        const float nl = NLs[l];
        const float s0 = p0 * nl, s1 = p1 * nl, s2 = p2 * nl;
        const float f0 = floorf(s0), f1 = floorf(s1), f2 = floorf(s2);
        const float l0 = s0 - f0, l1 = s1 - f1, l2 = s2 - f2;

        const unsigned va0 = (unsigned)(int)f0;
        const unsigned vb0 = va0 + 1u;
        const unsigned va1 = (unsigned)(int)f1 * P1;
        const unsigned vb1 = va1 + P1;
        const unsigned va2 = (unsigned)(int)f2 * P2;
        const unsigned vb2 = va2 + P2;

        const float2* tp = (const float2*)tbl + ((size_t)l << 19);

        const unsigned i000 = (va0 ^ va1 ^ va2) & TMASK;
        const unsigned i100 = (vb0 ^ va1 ^ va2) & TMASK;
        const unsigned i010 = (va0 ^ vb1 ^ va2) & TMASK;
        const unsigned i110 = (vb0 ^ vb1 ^ va2) & TMASK;
        const unsigned i001 = (va0 ^ va1 ^ vb2) & TMASK;
        const unsigned i101 = (vb0 ^ va1 ^ vb2) & TMASK;
        const unsigned i011 = (va0 ^ vb1 ^ vb2) & TMASK;
        const unsigned i111 = (vb0 ^ vb1 ^ vb2) & TMASK;

        const float2 c000 = tp[i000];
        const float2 c100 = tp[i100];
        const float2 c010 = tp[i010];
        const float2 c110 = tp[i110];
        const float2 c001 = tp[i001];
        const float2 c101 = tp[i101];
        const float2 c011 = tp[i011];
        const float2 c111 = tp[i111];

        const float m0 = 1.0f - l0, m1 = 1.0f - l1, m2 = 1.0f - l2;
        float a = 0.0f, b = 0.0f, w;
        w = m0 * m1 * m2; a = fmaf(w, c000.x, a); b = fmaf(w, c000.y, b);
        w = l0 * m1 * m2; a = fmaf(w, c100.x, a); b = fmaf(w, c100.y, b);
        w = m0 * l1 * m2; a = fmaf(w, c010.x, a); b = fmaf(w, c010.y, b);
        w = l0 * l1 * m2; a = fmaf(w, c110.x, a); b = fmaf(w, c110.y, b);
        w = m0 * m1 * l2; a = fmaf(w, c001.x, a); b = fmaf(w, c001.y, b);
        w = l0 * m1 * l2; a = fmaf(w, c101.x, a); b = fmaf(w, c101.y, b);
        w = m0 * l1 * l2; a = fmaf(w, c011.x, a); b = fmaf(w, c011.y, b);
        w = l0 * l1 * l2; a = fmaf(w, c111.x, a); b = fmaf(w, c111.y, b);
        feats[2 * l + 0] = a;
        feats[2 * l + 1] = b;
    }

    // ---- density MLP: 32 -> 64 (relu) -> 16 ----
    float hid[64];
    #pragma unroll
    for (int o = 0; o < 64; ++o) hid[o] = db1[o];
    #pragma unroll
    for (int i = 0; i < 32; ++i) {
        const float a = feats[i];
        #pragma unroll
        for (int o = 0; o < 64; ++o) hid[o] = fmaf(a, dW1[i * 64 + o], hid[o]);
    }
    float h[16];
    #pragma unroll
    for (int o = 0; o < 16; ++o) h[o] = db2[o];
    #pragma unroll
    for (int i = 0; i < 64; ++i) {
        const float a = fmaxf(hid[i], 0.0f);
        #pragma unroll
        for (int o = 0; o < 16; ++o) h[o] = fmaf(a, dW2[i * 16 + o], h[o]);
    }

    // ---- direction positional encoding: 27 dims ----
    float ch[43];
    #pragma unroll
    for (int o = 0; o < 16; ++o) ch[o] = h[o];
    ch[16] = d0; ch[17] = d1; ch[18] = d2;
    #pragma unroll
    for (int j = 0; j < 4; ++j) {
        const float s = (float)(1 << j);
        ch[19 + 6 * j + 0] = __sinf(s * d0);
        ch[19 + 6 * j + 1] = __sinf(s * d1);
        ch[19 + 6 * j + 2] = __sinf(s * d2);
        ch[19 + 6 * j + 3] = __cosf(s * d0);
        ch[19 + 6 * j + 4] = __cosf(s * d1);
        ch[19 + 6 * j + 5] = __cosf(s * d2);
    }

    // ---- color MLP: 43 -> 64 (relu) -> 64 (relu) -> 3 (sigmoid) ----
    float c1[64];
    #pragma unroll
    for (int o = 0; o < 64; ++o) c1[o] = cb1[o];
    #pragma unroll
    for (int i = 0; i < 43; ++i) {
        const float a = ch[i];
        #pragma unroll
        for (int o = 0; o < 64; ++o) c1[o] = fmaf(a, cW1[i * 64 + o], c1[o]);
    }
    float c2[64];
    #pragma unroll
    for (int o = 0; o < 64; ++o) c2[o] = cb2[o];
    #pragma unroll
    for (int i = 0; i < 64; ++i) {
        const float a = fmaxf(c1[i], 0.0f);
        #pragma unroll
        for (int o = 0; o < 64; ++o) c2[o] = fmaf(a, cW2[i * 64 + o], c2[o]);
    }
    float r0 = cb3[0], r1 = cb3[1], r2 = cb3[2];
    #pragma unroll
    for (int i = 0; i < 64; ++i) {
        const float a = fmaxf(c2[i], 0.0f);
        r0 = fmaf(a, cW3[i * 3 + 0], r0);
        r1 = fmaf(a, cW3[i * 3 + 1], r1);
        r2 = fmaf(a, cW3[i * 3 + 2], r2);
    }
    r0 = sigmoidf_fast(r0);
    r1 = sigmoidf_fast(r1);
    r2 = sigmoidf_fast(r2);

    if (!mask) { r0 = 0.0f; r1 = 0.0f; r2 = 0.0f; }
    out[3 * gid + 0] = r0;
    out[3 * gid + 1] = r1;
    out[3 * gid + 2] = r2;
    out[3 * NPTS + gid] = mask ? __expf(h[0]) : 0.0f;
}

extern "C" void kernel_launch(void* const* d_in, const int* in_sizes, int n_in,
                              void* d_out, int out_size, void* d_ws, size_t ws_size,
                              hipStream_t stream) {
    const float* x    = (const float*)d_in[0];
    const float* d    = (const float*)d_in[1];
    const float* tbl  = (const float*)d_in[2];
    const float* dW1  = (const float*)d_in[3];
    const float* db1  = (const float*)d_in[4];
    const float* dW2  = (const float*)d_in[5];
    const float* db2  = (const float*)d_in[6];
    const float* cW1  = (const float*)d_in[7];
    const float* cb1  = (const float*)d_in[8];
    const float* cW2  = (const float*)d_in[9];
    const float* cb2  = (const float*)d_in[10];
    const float* cW3  = (const float*)d_in[11];
    const float* cb3  = (const float*)d_in[12];

    ngp_fused<<<NPTS / 256, 256, 0, stream>>>(
        x, d, tbl, dW1, db1, dW2, db2, cW1, cb1, cW2, cb2, cW3, cb3,
        (float*)d_out);
}

// Round 2
// 204.022 us; speedup vs baseline: 1.1408x; 1.1408x over previous
//
#include <hip/hip_runtime.h>

#define NPTS 262144
#define P1 2654435761u
#define P2 805459861u
#define TMASK 0x7FFFFu

__device__ __forceinline__ float sigmoidf_fast(float v) {
    return 1.0f / (1.0f + __expf(-v));
}

// ---------------- Kernel A: hash-grid encode ----------------
// grid = 16 levels x 1024 blocks; level is block-uniform (SGPR).
// One thread = one (point, level): 8 independent gathers in flight.
// feats layout: [L][N] float2  (coalesced write here, 16 coalesced
// stream-reads in kernel B).
extern "C" __global__ void __launch_bounds__(256) ngp_encode(
    const float* __restrict__ xin, const float* __restrict__ tbl,
    float2* __restrict__ feats)
{
    const int l  = blockIdx.x >> 10;
    const int pt = ((blockIdx.x & 1023) << 8) + (int)threadIdx.x;

    const float x0 = xin[3 * pt + 0];
    const float x1 = xin[3 * pt + 1];
    const float x2 = xin[3 * pt + 2];
    const float xn0 = x0 / 3.0f, xn1 = x1 / 3.0f, xn2 = x2 / 3.0f;
    const bool mask = (fabsf(xn0) < 0.5f) & (fabsf(xn1) < 0.5f) & (fabsf(xn2) < 0.5f);
    if (!mask) return;   // masked-out points never influence the output

    static const float NLs[16] = {16.f, 22.f, 30.f, 42.f, 58.f, 80.f, 111.f, 153.f,
                                  212.f, 294.f, 406.f, 561.f, 776.f, 1072.f, 1482.f, 2048.f};
    const float nl = NLs[l];   // uniform per block -> scalar

    const float s0 = (xn0 + 0.5f) * nl;
    const float s1 = (xn1 + 0.5f) * nl;
    const float s2 = (xn2 + 0.5f) * nl;
    const float f0 = floorf(s0), f1 = floorf(s1), f2 = floorf(s2);
    const float l0 = s0 - f0, l1 = s1 - f1, l2 = s2 - f2;

    const unsigned va0 = (unsigned)(int)f0;
    const unsigned vb0 = va0 + 1u;
    const unsigned va1 = (unsigned)(int)f1 * P1;
    const unsigned vb1 = va1 + P1;
    const unsigned va2 = (unsigned)(int)f2 * P2;
    const unsigned vb2 = va2 + P2;

    const float2* tp = (const float2*)tbl + (size_t)l * 524288u;

    const unsigned i000 = (va0 ^ va1 ^ va2) & TMASK;
    const unsigned i100 = (vb0 ^ va1 ^ va2) & TMASK;
    const unsigned i010 = (va0 ^ vb1 ^ va2) & TMASK;
    const unsigned i110 = (vb0 ^ vb1 ^ va2) & TMASK;
    const unsigned i001 = (va0 ^ va1 ^ vb2) & TMASK;
    const unsigned i101 = (vb0 ^ va1 ^ vb2) & TMASK;
    const unsigned i011 = (va0 ^ vb1 ^ vb2) & TMASK;
    const unsigned i111 = (vb0 ^ vb1 ^ vb2) & TMASK;

    const float2 c000 = tp[i000];
    const float2 c100 = tp[i100];
    const float2 c010 = tp[i010];
    const float2 c110 = tp[i110];
    const float2 c001 = tp[i001];
    const float2 c101 = tp[i101];
    const float2 c011 = tp[i011];
    const float2 c111 = tp[i111];

    const float m0 = 1.0f - l0, m1 = 1.0f - l1, m2 = 1.0f - l2;
    float a = 0.0f, b = 0.0f, w;
    w = m0 * m1 * m2; a = fmaf(w, c000.x, a); b = fmaf(w, c000.y, b);
    w = l0 * m1 * m2; a = fmaf(w, c100.x, a); b = fmaf(w, c100.y, b);
    w = m0 * l1 * m2; a = fmaf(w, c010.x, a); b = fmaf(w, c010.y, b);
    w = l0 * l1 * m2; a = fmaf(w, c110.x, a); b = fmaf(w, c110.y, b);
    w = m0 * m1 * l2; a = fmaf(w, c001.x, a); b = fmaf(w, c001.y, b);
    w = l0 * m1 * l2; a = fmaf(w, c101.x, a); b = fmaf(w, c101.y, b);
    w = m0 * l1 * l2; a = fmaf(w, c011.x, a); b = fmaf(w, c011.y, b);
    w = l0 * l1 * l2; a = fmaf(w, c111.x, a); b = fmaf(w, c111.y, b);

    feats[(size_t)l * NPTS + pt] = make_float2(a, b);
}

// ---------------- Kernel B: fused MLPs ----------------
extern "C" __global__ void __launch_bounds__(256) ngp_mlp(
    const float* __restrict__ xin, const float* __restrict__ din,
    const float2* __restrict__ featsg,
    const float* __restrict__ dW1, const float* __restrict__ db1,
    const float* __restrict__ dW2, const float* __restrict__ db2,
    const float* __restrict__ cW1, const float* __restrict__ cb1,
    const float* __restrict__ cW2, const float* __restrict__ cb2,
    const float* __restrict__ cW3, const float* __restrict__ cb3,
    float* __restrict__ out)
{
    const int gid = blockIdx.x * 256 + (int)threadIdx.x;

    const float x0 = xin[3 * gid + 0];
    const float x1 = xin[3 * gid + 1];
    const float x2 = xin[3 * gid + 2];
    const float xn0 = x0 / 3.0f, xn1 = x1 / 3.0f, xn2 = x2 / 3.0f;
    const bool mask = (fabsf(xn0) < 0.5f) & (fabsf(xn1) < 0.5f) & (fabsf(xn2) < 0.5f);
    if (!mask) {
        out[3 * gid + 0] = 0.0f;
        out[3 * gid + 1] = 0.0f;
        out[3 * gid + 2] = 0.0f;
        out[3 * NPTS + gid] = 0.0f;
        return;
    }

    float feats[32];
    #pragma unroll
    for (int l = 0; l < 16; ++l) {
        const float2 f = featsg[(size_t)l * NPTS + gid];
        feats[2 * l + 0] = f.x;
        feats[2 * l + 1] = f.y;
    }

    // ---- density MLP: 32 -> 64 (relu) -> 16 ----
    float hid[64];
    #pragma unroll
    for (int o = 0; o < 64; ++o) hid[o] = db1[o];
    #pragma unroll
    for (int i = 0; i < 32; ++i) {
        const float a = feats[i];
        #pragma unroll
        for (int o = 0; o < 64; ++o) hid[o] = fmaf(a, dW1[i * 64 + o], hid[o]);
    }
    float h[16];
    #pragma unroll
    for (int o = 0; o < 16; ++o) h[o] = db2[o];
    #pragma unroll
    for (int i = 0; i < 64; ++i) {
        const float a = fmaxf(hid[i], 0.0f);
        #pragma unroll
        for (int o = 0; o < 16; ++o) h[o] = fmaf(a, dW2[i * 16 + o], h[o]);
    }

    // ---- direction positional encoding: 27 dims ----
    const float d0 = din[3 * gid + 0];
    const float d1 = din[3 * gid + 1];
    const float d2 = din[3 * gid + 2];
    float ch[43];
    #pragma unroll
    for (int o = 0; o < 16; ++o) ch[o] = h[o];
    ch[16] = d0; ch[17] = d1; ch[18] = d2;
    #pragma unroll
    for (int j = 0; j < 4; ++j) {
        const float s = (float)(1 << j);
        ch[19 + 6 * j + 0] = __sinf(s * d0);
        ch[19 + 6 * j + 1] = __sinf(s * d1);
        ch[19 + 6 * j + 2] = __sinf(s * d2);
        ch[19 + 6 * j + 3] = __cosf(s * d0);
        ch[19 + 6 * j + 4] = __cosf(s * d1);
        ch[19 + 6 * j + 5] = __cosf(s * d2);
    }

    // ---- color MLP: 43 -> 64 (relu) -> 64 (relu) -> 3 (sigmoid) ----
    float c1[64];
    #pragma unroll
    for (int o = 0; o < 64; ++o) c1[o] = cb1[o];
    #pragma unroll
    for (int i = 0; i < 43; ++i) {
        const float a = ch[i];
        #pragma unroll
        for (int o = 0; o < 64; ++o) c1[o] = fmaf(a, cW1[i * 64 + o], c1[o]);
    }
    float c2[64];
    #pragma unroll
    for (int o = 0; o < 64; ++o) c2[o] = cb2[o];
    #pragma unroll
    for (int i = 0; i < 64; ++i) {
        const float a = fmaxf(c1[i], 0.0f);
        #pragma unroll
        for (int o = 0; o < 64; ++o) c2[o] = fmaf(a, cW2[i * 64 + o], c2[o]);
    }
    float r0 = cb3[0], r1 = cb3[1], r2 = cb3[2];
    #pragma unroll
    for (int i = 0; i < 64; ++i) {
        const float a = fmaxf(c2[i], 0.0f);
        r0 = fmaf(a, cW3[i * 3 + 0], r0);
        r1 = fmaf(a, cW3[i * 3 + 1], r1);
        r2 = fmaf(a, cW3[i * 3 + 2], r2);
    }
    out[3 * gid + 0] = sigmoidf_fast(r0);
    out[3 * gid + 1] = sigmoidf_fast(r1);
    out[3 * gid + 2] = sigmoidf_fast(r2);
    out[3 * NPTS + gid] = __expf(h[0]);
}

extern "C" void kernel_launch(void* const* d_in, const int* in_sizes, int n_in,
                              void* d_out, int out_size, void* d_ws, size_t ws_size,
                              hipStream_t stream) {
    const float* x    = (const float*)d_in[0];
    const float* d    = (const float*)d_in[1];
    const float* tbl  = (const float*)d_in[2];
    const float* dW1  = (const float*)d_in[3];
    const float* db1  = (const float*)d_in[4];
    const float* dW2  = (const float*)d_in[5];
    const float* db2  = (const float*)d_in[6];
    const float* cW1  = (const float*)d_in[7];
    const float* cb1  = (const float*)d_in[8];
    const float* cW2  = (const float*)d_in[9];
    const float* cb2  = (const float*)d_in[10];
    const float* cW3  = (const float*)d_in[11];
    const float* cb3  = (const float*)d_in[12];

    float2* feats = (float2*)d_ws;   // 16 * 262144 * 8 B = 32 MB

    ngp_encode<<<16 * 1024, 256, 0, stream>>>(x, tbl, feats);
    ngp_mlp<<<NPTS / 256, 256, 0, stream>>>(
        x, d, feats, dW1, db1, dW2, db2, cW1, cb1, cW2, cb2, cW3, cb3,
        (float*)d_out);
}

// Round 3
// 108.065 us; speedup vs baseline: 2.1538x; 1.8880x over previous
//
#include <hip/hip_runtime.h>

#define NPTS 262144
#define HP1 2654435761u
#define HP2 805459861u
#define TMASK 0x7FFFFu

typedef __attribute__((ext_vector_type(8))) short short8;
typedef __attribute__((ext_vector_type(4))) float f32x4;
typedef unsigned short ushort_t;
typedef unsigned int uint_t;

#define MFMA(a, b, c) __builtin_amdgcn_mfma_f32_16x16x32_bf16((a), (b), (c), 0, 0, 0)

__device__ __forceinline__ ushort_t f2bf(float f) {
    uint_t u = __float_as_uint(f);
    return (ushort_t)((u + 0x7FFFu + ((u >> 16) & 1u)) >> 16);
}
__device__ __forceinline__ float sigmoidf_fast(float v) {
    return 1.0f / (1.0f + __expf(-v));
}

// Weight-fragment offsets in ws (ushort elements), after the 16 MB feats region.
#define OFF_DW1 0
#define OFF_DW2 2048
#define OFF_CW1 3072
#define OFF_CW2 7168
#define OFF_CW3 11264
#define WF_TOTAL 12288

// ---------------- Kernel 0: pack weights into bf16 MFMA B-fragments ----------------
// B-frag layout (16x16x32): lane holds col = lane&15, k = kc*32 + 8*(lane>>4) + j.
// Stored frag-major: wf[fragbase + lane*8 + j], 16B contiguous per lane.
extern "C" __global__ void ngp_prep(
    const float* __restrict__ dW1, const float* __restrict__ dW2,
    const float* __restrict__ cW1, const float* __restrict__ cW2,
    const float* __restrict__ cW3, ushort_t* __restrict__ wf)
{
    const int e = blockIdx.x * 256 + (int)threadIdx.x;
    if (e >= WF_TOTAL) return;
    const float* W; int base, NT, KR, NR;
    if (e < OFF_DW2)      { W = dW1; base = OFF_DW1; NT = 4; KR = 32; NR = 64; }
    else if (e < OFF_CW1) { W = dW2; base = OFF_DW2; NT = 1; KR = 64; NR = 16; }
    else if (e < OFF_CW2) { W = cW1; base = OFF_CW1; NT = 4; KR = 43; NR = 64; }
    else if (e < OFF_CW3) { W = cW2; base = OFF_CW2; NT = 4; KR = 64; NR = 64; }
    else                  { W = cW3; base = OFF_CW3; NT = 1; KR = 64; NR = 3;  }
    const int r = e - base;
    const int frag = r >> 9;
    const int lane = (r >> 3) & 63;
    const int j = r & 7;
    const int kc = frag / NT, nt = frag % NT;
    const int k = kc * 32 + ((lane >> 4) << 3) + j;
    const int n = nt * 16 + (lane & 15);
    const float v = (k < KR && n < NR) ? W[k * NR + n] : 0.0f;
    wf[e] = f2bf(v);
}

// ---------------- Kernel A: hash-grid encode (bf16-packed output) ----------------
extern "C" __global__ void __launch_bounds__(256) ngp_encode(
    const float* __restrict__ xin, const float* __restrict__ tbl,
    uint_t* __restrict__ feats)
{
    const int l  = blockIdx.x >> 10;
    const int pt = ((blockIdx.x & 1023) << 8) + (int)threadIdx.x;

    const float x0 = xin[3 * pt + 0];
    const float x1 = xin[3 * pt + 1];
    const float x2 = xin[3 * pt + 2];
    const float xn0 = x0 / 3.0f, xn1 = x1 / 3.0f, xn2 = x2 / 3.0f;
    const bool mask = (fabsf(xn0) < 0.5f) & (fabsf(xn1) < 0.5f) & (fabsf(xn2) < 0.5f);
    if (!mask) return;   // masked points never influence the output

    static const float NLs[16] = {16.f, 22.f, 30.f, 42.f, 58.f, 80.f, 111.f, 153.f,
                                  212.f, 294.f, 406.f, 561.f, 776.f, 1072.f, 1482.f, 2048.f};
    const float nl = NLs[l];

    const float s0 = (xn0 + 0.5f) * nl;
    const float s1 = (xn1 + 0.5f) * nl;
    const float s2 = (xn2 + 0.5f) * nl;
    const float f0 = floorf(s0), f1 = floorf(s1), f2 = floorf(s2);
    const float l0 = s0 - f0, l1 = s1 - f1, l2 = s2 - f2;

    const unsigned va0 = (unsigned)(int)f0;
    const unsigned vb0 = va0 + 1u;
    const unsigned va1 = (unsigned)(int)f1 * HP1;
    const unsigned vb1 = va1 + HP1;
    const unsigned va2 = (unsigned)(int)f2 * HP2;
    const unsigned vb2 = va2 + HP2;

    const float2* tp = (const float2*)tbl + (size_t)l * 524288u;

    const unsigned i000 = (va0 ^ va1 ^ va2) & TMASK;
    const unsigned i100 = (vb0 ^ va1 ^ va2) & TMASK;
    const unsigned i010 = (va0 ^ vb1 ^ va2) & TMASK;
    const unsigned i110 = (vb0 ^ vb1 ^ va2) & TMASK;
    const unsigned i001 = (va0 ^ va1 ^ vb2) & TMASK;
    const unsigned i101 = (vb0 ^ va1 ^ vb2) & TMASK;
    const unsigned i011 = (va0 ^ vb1 ^ vb2) & TMASK;
    const unsigned i111 = (vb0 ^ vb1 ^ vb2) & TMASK;

    const float2 c000 = tp[i000];
    const float2 c100 = tp[i100];
    const float2 c010 = tp[i010];
    const float2 c110 = tp[i110];
    const float2 c001 = tp[i001];
    const float2 c101 = tp[i101];
    const float2 c011 = tp[i011];
    const float2 c111 = tp[i111];

    const float m0 = 1.0f - l0, m1 = 1.0f - l1, m2 = 1.0f - l2;
    float a = 0.0f, b = 0.0f, w;
    w = m0 * m1 * m2; a = fmaf(w, c000.x, a); b = fmaf(w, c000.y, b);
    w = l0 * m1 * m2; a = fmaf(w, c100.x, a); b = fmaf(w, c100.y, b);
    w = m0 * l1 * m2; a = fmaf(w, c010.x, a); b = fmaf(w, c010.y, b);
    w = l0 * l1 * m2; a = fmaf(w, c110.x, a); b = fmaf(w, c110.y, b);
    w = m0 * m1 * l2; a = fmaf(w, c001.x, a); b = fmaf(w, c001.y, b);
    w = l0 * m1 * l2; a = fmaf(w, c101.x, a); b = fmaf(w, c101.y, b);
    w = m0 * l1 * l2; a = fmaf(w, c011.x, a); b = fmaf(w, c011.y, b);
    w = l0 * l1 * l2; a = fmaf(w, c111.x, a); b = fmaf(w, c111.y, b);

    feats[(size_t)l * NPTS + pt] = (uint_t)f2bf(a) | ((uint_t)f2bf(b) << 16);
}

// ---------------- Kernel B: MFMA MLPs ----------------
// Per wave: 64 points. LDS act tile [64 rows(pts)][64 cols] bf16, XOR-swizzled
// (byte ^= (row&7)<<4) to kill the 16-way row-stride-128B bank conflict.
// A-frag (16x16x32): lane holds row = lane&15 (+16*mt), k = kc*32 + 8*(lane>>4)+j.
// D-frag: col = lane&15 (+16*nt), row = 4*(lane>>4)+reg (+16*mt)  [m89-verified].
extern "C" __global__ void __launch_bounds__(256) ngp_mlp(
    const float* __restrict__ xin, const float* __restrict__ din,
    const uint_t* __restrict__ featsbf, const ushort_t* __restrict__ wf,
    const float* __restrict__ db1, const float* __restrict__ db2,
    const float* __restrict__ cb1, const float* __restrict__ cb2,
    const float* __restrict__ cb3,
    float* __restrict__ out)
{
    __shared__ short act[4][4096];
    __shared__ float mk[4][64];

    const int w    = (int)threadIdx.x >> 6;
    const int lane = (int)threadIdx.x & 63;
    const int lrow = lane & 15;
    const int lq   = lane >> 4;
    const int ptb  = blockIdx.x * 256 + w * 64;
    const int p    = ptb + lane;
    char* Ab = (char*)&act[w][0];

#define LDSA(mt, kc) (*reinterpret_cast<const short8*>(Ab + ((((mt) * 16 + lrow) * 128 + (kc) * 64 + lq * 16) ^ ((lrow & 7) << 4))))
#define LOADB(off)   (*reinterpret_cast<const short8*>(wf + (off) + lane * 8))
#define STB16(row, col, val) *reinterpret_cast<ushort_t*>(Ab + ((((row) * 128 + (col) * 2)) ^ (((row) & 7) << 4))) = (val)

    // ---- mask + feats -> LDS rows (this lane owns point p = row `lane`) ----
    const float x0 = xin[3 * p + 0];
    const float x1 = xin[3 * p + 1];
    const float x2 = xin[3 * p + 2];
    const bool msk = (fabsf(x0) < 1.5f) & (fabsf(x1) < 1.5f) & (fabsf(x2) < 1.5f);
    mk[w][lane] = msk ? 1.0f : 0.0f;

    uint_t u[16];
    #pragma unroll
    for (int l = 0; l < 16; ++l) u[l] = featsbf[(size_t)l * NPTS + p];
    #pragma unroll
    for (int c = 0; c < 4; ++c) {
        short8 v;
        #pragma unroll
        for (int q = 0; q < 4; ++q) {
            v[2 * q + 0] = (short)(u[4 * c + q] & 0xFFFFu);
            v[2 * q + 1] = (short)(u[4 * c + q] >> 16);
        }
        const int byte = (lane * 128 + 16 * c) ^ ((lane & 7) << 4);
        *reinterpret_cast<short8*>(Ab + byte) = v;
    }
    const float d0v = din[3 * p + 0];
    const float d1v = din[3 * p + 1];
    const float d2v = din[3 * p + 2];

    __syncthreads();

    // ---- Layer D1: feats[64x32] @ dW1[32x64] ----
    f32x4 acc[4][4];
    #pragma unroll
    for (int nt = 0; nt < 4; ++nt) {
        const float b = db1[nt * 16 + lrow];
        #pragma unroll
        for (int mt = 0; mt < 4; ++mt) acc[mt][nt] = (f32x4){b, b, b, b};
    }
    {
        short8 a0 = LDSA(0, 0), a1 = LDSA(1, 0), a2 = LDSA(2, 0), a3 = LDSA(3, 0);
        #pragma unroll
        for (int nt = 0; nt < 4; ++nt) {
            const short8 B = LOADB(OFF_DW1 + nt * 512);
            acc[0][nt] = MFMA(a0, B, acc[0][nt]);
            acc[1][nt] = MFMA(a1, B, acc[1][nt]);
            acc[2][nt] = MFMA(a2, B, acc[2][nt]);
            acc[3][nt] = MFMA(a3, B, acc[3][nt]);
        }
    }
    __syncthreads();
    // write relu(hid) as bf16
    #pragma unroll
    for (int mt = 0; mt < 4; ++mt)
        #pragma unroll
        for (int nt = 0; nt < 4; ++nt)
            #pragma unroll
            for (int r = 0; r < 4; ++r) {
                const int row = mt * 16 + lq * 4 + r;
                STB16(row, nt * 16 + lrow, f2bf(fmaxf(acc[mt][nt][r], 0.0f)));
            }
    __syncthreads();

    // ---- Layer D2: hid[64x64] @ dW2[64x16] ----
    f32x4 hD[4];
    {
        const float b = db2[lrow];
        #pragma unroll
        for (int mt = 0; mt < 4; ++mt) hD[mt] = (f32x4){b, b, b, b};
        #pragma unroll
        for (int kc = 0; kc < 2; ++kc) {
            const short8 B = LOADB(OFF_DW2 + kc * 512);
            #pragma unroll
            for (int mt = 0; mt < 4; ++mt) hD[mt] = MFMA(LDSA(mt, kc), B, hD[mt]);
        }
    }
    __syncthreads();   // all hid reads done; safe to overwrite tile with ch

    // sigma store (lanes holding col 0 of h)
    if (lrow == 0) {
        #pragma unroll
        for (int mt = 0; mt < 4; ++mt)
            #pragma unroll
            for (int r = 0; r < 4; ++r) {
                const int row = mt * 16 + lq * 4 + r;
                const float mm = mk[w][row];
                out[3 * NPTS + ptb + row] = (mm != 0.0f) ? __expf(hD[mt][r]) : 0.0f;
            }
    }
    // h -> ch cols 0..15 (raw, no relu)
    #pragma unroll
    for (int mt = 0; mt < 4; ++mt)
        #pragma unroll
        for (int r = 0; r < 4; ++r) {
            const int row = mt * 16 + lq * 4 + r;
            STB16(row, lrow, f2bf(hD[mt][r]));
        }
    // d_enc -> ch cols 16..42, zeros 43..63 (own row = lane)
    {
        ushort_t t[48];
        t[0] = f2bf(d0v); t[1] = f2bf(d1v); t[2] = f2bf(d2v);
        #pragma unroll
        for (int j = 0; j < 4; ++j) {
            const float s = (float)(1 << j);
            t[3 + 6 * j + 0] = f2bf(__sinf(s * d0v));
            t[3 + 6 * j + 1] = f2bf(__sinf(s * d1v));
            t[3 + 6 * j + 2] = f2bf(__sinf(s * d2v));
            t[3 + 6 * j + 3] = f2bf(__cosf(s * d0v));
            t[3 + 6 * j + 4] = f2bf(__cosf(s * d1v));
            t[3 + 6 * j + 5] = f2bf(__cosf(s * d2v));
        }
        #pragma unroll
        for (int i = 27; i < 48; ++i) t[i] = 0;
        #pragma unroll
        for (int c = 0; c < 6; ++c) {
            short8 v;
            #pragma unroll
            for (int j = 0; j < 8; ++j) v[j] = (short)t[8 * c + j];
            const int byte = (lane * 128 + 32 + 16 * c) ^ ((lane & 7) << 4);
            *reinterpret_cast<short8*>(Ab + byte) = v;
        }
    }
    __syncthreads();

    // ---- Layer C1: ch[64x64(43)] @ cW1[64x64] ----
    #pragma unroll
    for (int nt = 0; nt < 4; ++nt) {
        const float b = cb1[nt * 16 + lrow];
        #pragma unroll
        for (int mt = 0; mt < 4; ++mt) acc[mt][nt] = (f32x4){b, b, b, b};
    }
    #pragma unroll
    for (int kc = 0; kc < 2; ++kc) {
        short8 a0 = LDSA(0, kc), a1 = LDSA(1, kc), a2 = LDSA(2, kc), a3 = LDSA(3, kc);
        #pragma unroll
        for (int nt = 0; nt < 4; ++nt) {
            const short8 B = LOADB(OFF_CW1 + (kc * 4 + nt) * 512);
            acc[0][nt] = MFMA(a0, B, acc[0][nt]);
            acc[1][nt] = MFMA(a1, B, acc[1][nt]);
            acc[2][nt] = MFMA(a2, B, acc[2][nt]);
            acc[3][nt] = MFMA(a3, B, acc[3][nt]);
        }
    }
    __syncthreads();
    #pragma unroll
    for (int mt = 0; mt < 4; ++mt)
        #pragma unroll
        for (int nt = 0; nt < 4; ++nt)
            #pragma unroll
            for (int r = 0; r < 4; ++r) {
                const int row = mt * 16 + lq * 4 + r;
                STB16(row, nt * 16 + lrow, f2bf(fmaxf(acc[mt][nt][r], 0.0f)));
            }
    __syncthreads();

    // ---- Layer C2: c1[64x64] @ cW2[64x64] ----
    #pragma unroll
    for (int nt = 0; nt < 4; ++nt) {
        const float b = cb2[nt * 16 + lrow];
        #pragma unroll
        for (int mt = 0; mt < 4; ++mt) acc[mt][nt] = (f32x4){b, b, b, b};
    }
    #pragma unroll
    for (int kc = 0; kc < 2; ++kc) {
        short8 a0 = LDSA(0, kc), a1 = LDSA(1, kc), a2 = LDSA(2, kc), a3 = LDSA(3, kc);
        #pragma unroll
        for (int nt = 0; nt < 4; ++nt) {
            const short8 B = LOADB(OFF_CW2 + (kc * 4 + nt) * 512);
            acc[0][nt] = MFMA(a0, B, acc[0][nt]);
            acc[1][nt] = MFMA(a1, B, acc[1][nt]);
            acc[2][nt] = MFMA(a2, B, acc[2][nt]);
            acc[3][nt] = MFMA(a3, B, acc[3][nt]);
        }
    }
    __syncthreads();
    #pragma unroll
    for (int mt = 0; mt < 4; ++mt)
        #pragma unroll
        for (int nt = 0; nt < 4; ++nt)
            #pragma unroll
            for (int r = 0; r < 4; ++r) {
                const int row = mt * 16 + lq * 4 + r;
                STB16(row, nt * 16 + lrow, f2bf(fmaxf(acc[mt][nt][r], 0.0f)));
            }
    __syncthreads();

    // ---- Layer C3: c2[64x64] @ cW3[64x3(pad16)] ----
    f32x4 rD[4];
    {
        const float b = (lrow < 3) ? cb3[lrow] : 0.0f;
        #pragma unroll
        for (int mt = 0; mt < 4; ++mt) rD[mt] = (f32x4){b, b, b, b};
        #pragma unroll
        for (int kc = 0; kc < 2; ++kc) {
            const short8 B = LOADB(OFF_CW3 + kc * 512);
            #pragma unroll
            for (int mt = 0; mt < 4; ++mt) rD[mt] = MFMA(LDSA(mt, kc), B, rD[mt]);
        }
    }
    if (lrow < 3) {
        #pragma unroll
        for (int mt = 0; mt < 4; ++mt)
            #pragma unroll
            for (int r = 0; r < 4; ++r) {
                const int row = mt * 16 + lq * 4 + r;
                const float mm = mk[w][row];
                out[3 * (ptb + row) + lrow] = (mm != 0.0f) ? sigmoidf_fast(rD[mt][r]) : 0.0f;
            }
    }
#undef LDSA
#undef LOADB
#undef STB16
}

extern "C" void kernel_launch(void* const* d_in, const int* in_sizes, int n_in,
                              void* d_out, int out_size, void* d_ws, size_t ws_size,
                              hipStream_t stream) {
    const float* x    = (const float*)d_in[0];
    const float* d    = (const float*)d_in[1];
    const float* tbl  = (const float*)d_in[2];
    const float* dW1  = (const float*)d_in[3];
    const float* db1  = (const float*)d_in[4];
    const float* dW2  = (const float*)d_in[5];
    const float* db2  = (const float*)d_in[6];
    const float* cW1  = (const float*)d_in[7];
    const float* cb1  = (const float*)d_in[8];
    const float* cW2  = (const float*)d_in[9];
    const float* cb2  = (const float*)d_in[10];
    const float* cW3  = (const float*)d_in[11];
    const float* cb3  = (const float*)d_in[12];

    uint_t* feats = (uint_t*)d_ws;                                   // 16 MB
    ushort_t* wfr = (ushort_t*)((char*)d_ws + 16u * 1024u * 1024u);  // 24 KB

    ngp_prep<<<48, 256, 0, stream>>>(dW1, dW2, cW1, cW2, cW3, wfr);
    ngp_encode<<<16 * 1024, 256, 0, stream>>>(x, tbl, feats);
    ngp_mlp<<<NPTS / 256, 256, 0, stream>>>(
        x, d, feats, wfr, db1, db2, cb1, cb2, cb3, (float*)d_out);
}